// Round 4
// baseline (512.966 us; speedup 1.0000x reference)
//
#include <hip/hip_runtime.h>

// Problem constants (fixed by the reference)
#define D_   8
#define Q_   1024
#define DB_  32768
#define F_   64
#define NB_  128      // num_buckets = num_neighbors
#define BS_  256      // bucket_size = DB/NB
#define NT_  (Q_*D_*NB_)   // 1,048,576 (q,d,j) triples
#define SPLIT_ 4      // split of the b-range across blocks
#define MARGIN_ 4e-3f // top-2 gap below which we escalate to fp64 exact path
                      // (split-bf16 score err <= ~5e-4, so margin still safe)

typedef __attribute__((ext_vector_type(16))) float  f32x16;
typedef __attribute__((ext_vector_type(8)))  short  short8;
typedef __attribute__((ext_vector_type(4)))  short  short4v;
typedef __attribute__((ext_vector_type(8)))  __bf16 bf16x8;

static __device__ __forceinline__ short f2bf(float x) {   // RNE float->bf16
    unsigned u = __float_as_uint(x);
    u += 0x7fffu + ((u >> 16) & 1u);
    return (short)(u >> 16);
}
static __device__ __forceinline__ float bf2f(short h) {
    return __uint_as_float(((unsigned)(unsigned short)h) << 16);
}
static __device__ __forceinline__ f32x16 mfma32(short8 a, short8 b, f32x16 c) {
    return __builtin_amdgcn_mfma_f32_32x32x16_bf16(
        __builtin_bit_cast(bf16x8, a), __builtin_bit_cast(bf16x8, b), c, 0, 0, 0);
}

// ---------------------------------------------------------------------------
// Split-bf16 conversion: x = hi + lo, both bf16 (RNE). Keys: elementwise.
// ---------------------------------------------------------------------------
__global__ void k_conv(const float* __restrict__ src, short* __restrict__ hi,
                       short* __restrict__ lo, int n4)
{
    for (int i = blockIdx.x * 256 + threadIdx.x; i < n4; i += gridDim.x * 256) {
        float4 v = ((const float4*)src)[i];
        short4v h, l;
        h.x = f2bf(v.x); l.x = f2bf(v.x - bf2f(h.x));
        h.y = f2bf(v.y); l.y = f2bf(v.y - bf2f(h.y));
        h.z = f2bf(v.z); l.z = f2bf(v.z - bf2f(h.z));
        h.w = f2bf(v.w); l.w = f2bf(v.w - bf2f(h.w));
        *(short4v*)(hi + (size_t)i * 4) = h;
        *(short4v*)(lo + (size_t)i * 4) = l;
    }
}

// Query conversion with (Q,D,F) -> (D,Q,F) transpose.
__global__ void k_convq(const float* __restrict__ q, short* __restrict__ hi,
                        short* __restrict__ lo)
{
    int i = blockIdx.x * 256 + threadIdx.x;   // exactly Q_*D_*F_/4 threads
    int c = i & 15, d = (i >> 4) & 7, qq = i >> 7;
    float4 v = *(const float4*)(q + ((size_t)qq * D_ + d) * F_ + c * 4);
    short4v h, l;
    h.x = f2bf(v.x); l.x = f2bf(v.x - bf2f(h.x));
    h.y = f2bf(v.y); l.y = f2bf(v.y - bf2f(h.y));
    h.z = f2bf(v.z); l.z = f2bf(v.z - bf2f(h.z));
    h.w = f2bf(v.w); l.w = f2bf(v.w - bf2f(h.w));
    size_t o = ((size_t)d * Q_ + qq) * F_ + c * 4;
    *(short4v*)(hi + o) = h;
    *(short4v*)(lo + o) = l;
}

// ---------------------------------------------------------------------------
// K1: MFMA scan, LDS-FREE. Block = 64q x 64j, 4 waves each owning one 32x32
// tile. B-fragments (key rows) are loaded straight from global per step
// (8 x global_load_dwordx4/lane, 8KB/wave/step) -- served by L1/L2 since the
// 16 q-blocks sharing a K-slice are co-resident on one XCD (swizzle). No
// barriers in the loop (one light re-convergence sync every 16 steps), no
// ds_write/ds_read, no vmcnt(0) drains. All 3 split-bf16 passes accumulate
// into ONE C (the MFMA C-operand is the adder). 3 waves/SIMD via VGPR cap.
// ---------------------------------------------------------------------------
__global__ __launch_bounds__(256, 3) void k_scan_mfma(
    const short* __restrict__ khi, const short* __restrict__ klo,
    const short* __restrict__ qhi, const short* __restrict__ qlo,
    float* __restrict__ m1p, float* __restrict__ m2p, int* __restrict__ b1p)
{
    const int tid = threadIdx.x;
    // XCD swizzle (1024 = 8 XCD x 128): contiguous w per XCD -> same-key
    // q-tiles co-resident on one XCD (bijective: 1024 % 8 == 0).
    const int w    = ((blockIdx.x & 7) << 7) | (blockIdx.x >> 3);
    const int qi   = w & 15;
    const int ji   = (w >> 4) & 1;
    const int d    = (w >> 5) & 7;
    const int half = w >> 8;               // 0..SPLIT_-1
    const int q0 = qi * 64, j0 = ji * 64;
    const int wv = tid >> 6, lane = tid & 63;
    const int qg = wv >> 1, jg = wv & 1;
    const int lrow = lane & 31, kg = lane >> 5;

    // hoist Q fragments (A-operand): row = l&31, 8 bf16 at k = ks*16 + (l>>5)*8
    short8 qh[4], ql[4];
    {
        const size_t qoff = ((size_t)d * Q_ + q0 + qg * 32 + lrow) * F_ + kg * 8;
#pragma unroll
        for (int ks = 0; ks < 4; ++ks) {
            qh[ks] = *(const short8*)(qhi + qoff + ks * 16);
            ql[ks] = *(const short8*)(qlo + qoff + ks * 16);
        }
    }

    float m1[16], m2[16]; int b1[16];
#pragma unroll
    for (int r = 0; r < 16; ++r) { m1[r] = -3e38f; m2[r] = -3e38f; b1[r] = 0; }

    const int nsteps = BS_ / SPLIT_;       // 64
    const int bstart = half * nsteps;
    // this lane's key row n = b*128 + (j0 + jg*32 + lrow), col chunk kg*8
    const int nrow = bstart * NB_ + j0 + jg * 32 + lrow;
    const short* ph = khi + ((size_t)d * DB_ + nrow) * F_ + kg * 8;
    const short* pl = klo + ((size_t)d * DB_ + nrow) * F_ + kg * 8;
    const size_t kstep = (size_t)NB_ * F_;   // shorts per bucket step (8192)

    for (int bb = 0; bb < nsteps; ++bb) {
        // B-fragments straight from global (L1/L2-hot); imm offsets 0/32/64/96B
        short8 kh0 = *(const short8*)(ph);
        short8 kh1 = *(const short8*)(ph + 16);
        short8 kh2 = *(const short8*)(ph + 32);
        short8 kh3 = *(const short8*)(ph + 48);
        short8 kl0 = *(const short8*)(pl);
        short8 kl1 = *(const short8*)(pl + 16);
        short8 kl2 = *(const short8*)(pl + 32);
        short8 kl3 = *(const short8*)(pl + 48);
        ph += kstep; pl += kstep;

        f32x16 c = {0,0,0,0,0,0,0,0,0,0,0,0,0,0,0,0};
        c = mfma32(qh[0], kh0, c);
        c = mfma32(qh[1], kh1, c);
        c = mfma32(qh[2], kh2, c);
        c = mfma32(qh[3], kh3, c);
        c = mfma32(ql[0], kh0, c);
        c = mfma32(ql[1], kh1, c);
        c = mfma32(ql[2], kh2, c);
        c = mfma32(ql[3], kh3, c);
        c = mfma32(qh[0], kl0, c);
        c = mfma32(qh[1], kl1, c);
        c = mfma32(qh[2], kl2, c);
        c = mfma32(qh[3], kl3, c);

        const int b = bstart + bb;
        // branchless top-2: med3 computes the new 2nd-max in ONE instruction
#pragma unroll
        for (int r = 0; r < 16; ++r) {
            float v = c[r];
            b1[r] = (v > m1[r]) ? b : b1[r];
            m2[r] = __builtin_amdgcn_fmed3f(v, m1[r], m2[r]);
            m1[r] = fmaxf(m1[r], v);
        }

        // light re-convergence: keep the block's 4 waves temporally tight so
        // the shared 32KB/step tile window stays L1/L2-hot
        if ((bb & 15) == 15) __syncthreads();
    }

    // write partials; C layout (verified): col=lane&31, row=(r&3)+8*(r>>2)+4*kg
#pragma unroll
    for (int r = 0; r < 16; ++r) {
        const int q = q0 + qg * 32 + 4 * kg + (r & 3) + 8 * (r >> 2);
        const size_t t = (((size_t)q * D_ + d) << 7) + j0 + jg * 32 + lrow;
        const size_t p = (size_t)half * NT_ + t;
        m1p[p] = m1[r]; m2p[p] = m2[r]; b1p[p] = b1[r];
    }
}

// ---------------------------------------------------------------------------
// Merge split-b partials -> final argmax index + near-tie flag list.
// ---------------------------------------------------------------------------
__global__ void k_merge(const float* __restrict__ m1p, const float* __restrict__ m2p,
                        const int* __restrict__ b1p, int* __restrict__ idx0,
                        int* __restrict__ flag_cnt, int* __restrict__ flag_list)
{
    int t = blockIdx.x * 256 + threadIdx.x;
    if (t >= NT_) return;
    float m1 = -3e38f, m2 = -3e38f;
    int i1 = 0;
#pragma unroll
    for (int h = 0; h < SPLIT_; ++h) {
        float a    = m1p[(size_t)h * NT_ + t];
        float bsec = m2p[(size_t)h * NT_ + t];
        int   ib   = b1p[(size_t)h * NT_ + t];
        if (a > m1) { m2 = m1; m1 = a; i1 = ib; }
        else if (a > m2) m2 = a;
        if (bsec > m2) m2 = bsec;
    }
    idx0[t] = i1;
    if (m2 >= m1 - MARGIN_) {
        int pos = atomicAdd(flag_cnt, 1);
        if (pos < NT_) flag_list[pos] = t;
    }
}

// ---------------------------------------------------------------------------
// K2: gather. Writes all 512 MB of output (hard-argmax rows).
// ---------------------------------------------------------------------------
__global__ void k_gather(const float* __restrict__ key_db, const float* __restrict__ value_db,
                         const int* __restrict__ idx0, float4* __restrict__ out)
{
    const int total = NT_ * 16 * 2;   // 33,554,432 float4
    for (int e = blockIdx.x * 256 + threadIdx.x; e < total; e += gridDim.x * 256) {
        int half = e >> 24;
        int rem  = e & 0xFFFFFF;
        int t  = rem >> 4;
        int fc = rem & 15;
        int j = t & 127;
        int d = (t >> 7) & 7;
        int b = idx0[t];
        const float* db = half ? value_db : key_db;
        int n = b * NB_ + j;
        out[e] = *reinterpret_cast<const float4*>(db + ((size_t)d * DB_ + n) * F_ + fc * 4);
    }
}

// ---------------------------------------------------------------------------
// K3: exact fp64 fix-up for flagged near-tie triples. One wave per triple.
// ---------------------------------------------------------------------------
__global__ void k_fix(const float* __restrict__ query, const float* __restrict__ key_db,
                      const float* __restrict__ value_db, const int* __restrict__ flag_cnt,
                      const int* __restrict__ flag_list, float* __restrict__ out)
{
    int cnt = *flag_cnt;
    if (cnt > NT_) cnt = NT_;
    int gw   = (blockIdx.x * blockDim.x + threadIdx.x) >> 6;
    int lane = threadIdx.x & 63;
    int nw   = (gridDim.x * blockDim.x) >> 6;

    for (int w = gw; w < cnt; w += nw) {
        int t = flag_list[w];
        int j = t & 127, d = (t >> 7) & 7, qi = t >> 10;
        const float* qrow = query + ((size_t)qi * D_ + d) * F_;
        const float* kb = key_db + (size_t)d * DB_ * F_;
        const float* vb = value_db + (size_t)d * DB_ * F_;

        double sv[4];
#pragma unroll
        for (int i = 0; i < 4; ++i) {
            int b = lane * 4 + i;
            const float* krow = kb + ((size_t)b * NB_ + j) * F_;
            double a = 0.0;
            for (int k2 = 0; k2 < F_; ++k2) a += (double)qrow[k2] * (double)krow[k2];
            sv[i] = a;
        }
        double m = fmax(fmax(sv[0], sv[1]), fmax(sv[2], sv[3]));
        for (int off = 32; off; off >>= 1) m = fmax(m, __shfl_xor(m, off));
        double ev[4];
        double es = 0.0;
#pragma unroll
        for (int i = 0; i < 4; ++i) { ev[i] = exp((sv[i] - m) * 1e6); es += ev[i]; }
        for (int off = 32; off; off >>= 1) es += __shfl_xor(es, off);
        double inv = 1.0 / es;
#pragma unroll
        for (int i = 0; i < 4; ++i) ev[i] *= inv;

        double ak = 0.0, av = 0.0;
        for (int src = 0; src < 64; ++src) {
#pragma unroll
            for (int i = 0; i < 4; ++i) {
                double wv = __shfl(ev[i], src);
                if (wv != 0.0) {
                    int b = src * 4 + i;
                    size_t o = ((size_t)b * NB_ + j) * F_ + lane;
                    ak += wv * (double)kb[o];
                    av += wv * (double)vb[o];
                }
            }
        }
        out[(size_t)t * F_ + lane] = (float)ak;
        out[(size_t)NT_ * F_ + (size_t)t * F_ + lane] = (float)av;
    }
}

// ---------------------------------------------------------------------------
extern "C" void kernel_launch(void* const* d_in, const int* in_sizes, int n_in,
                              void* d_out, int out_size, void* d_ws, size_t ws_size,
                              hipStream_t stream)
{
    const float* query    = (const float*)d_in[0];
    const float* key_db   = (const float*)d_in[1];
    const float* value_db = (const float*)d_in[2];
    float* out = (float*)d_out;

    // ws layout (~8.4 MB): idx0[NT] | flag_cnt | flag_list[NT]
    int* idx0      = (int*)d_ws;
    int* flag_cnt  = (int*)((char*)d_ws + (size_t)NT_ * 4);
    int* flag_list = (int*)((char*)d_ws + (size_t)NT_ * 4 + 256);

    // Scratch parked in the not-yet-written front of d_out (~117 MB of 512 MB):
    // bf16 hi/lo copies of keys+queries, then split-b partials. k_gather
    // overwrites every byte of d_out afterwards; all reads happen before.
    short* khi = (short*)d_out;                          // 33.5 MB
    short* klo = khi + (size_t)D_ * DB_ * F_;            // 33.5 MB
    short* qhi = klo + (size_t)D_ * DB_ * F_;            // 1 MB
    short* qlo = qhi + (size_t)Q_ * D_ * F_;             // 1 MB
    float* m1p = (float*)(qlo + (size_t)Q_ * D_ * F_);   // 16 MB
    float* m2p = m1p + (size_t)SPLIT_ * NT_;             // 16 MB
    int*   b1p = (int*)(m2p + (size_t)SPLIT_ * NT_);     // 16 MB

    hipMemsetAsync(flag_cnt, 0, 4, stream);

    k_conv     <<<2048, 256, 0, stream>>>(key_db, khi, klo, D_ * DB_ * F_ / 4);
    k_convq    <<<512,  256, 0, stream>>>(query, qhi, qlo);
    k_scan_mfma<<<1024, 256, 0, stream>>>(khi, klo, qhi, qlo, m1p, m2p, b1p);
    k_merge    <<<NT_ / 256, 256, 0, stream>>>(m1p, m2p, b1p, idx0, flag_cnt, flag_list);
    k_gather   <<<2048, 256, 0, stream>>>(key_db, value_db, idx0, (float4*)d_out);
    k_fix      <<<256,  256, 0, stream>>>(query, key_db, value_db, flag_cnt, flag_list, out);
}